// Round 1
// baseline (2123.138 us; speedup 1.0000x reference)
//
#include <hip/hip_runtime.h>
#include <hip/hip_bf16.h>

constexpr int N = 2048;   // tokens
constexpr int C = 1024;   // model dim
constexpr int H = 2048;   // hidden dim
constexpr int E = 8;      // experts
constexpr float EPS = 1.1920929e-07f;

// GEMM tiling
constexpr int MT  = 64;   // M tile
constexpr int NTT = 64;   // N tile
constexpr int KC  = 16;   // K chunk
constexpr int LDT = 68;   // LDS leading dim (pad: 16B-aligned rows, 2-way banks = free)

// ---------------------------------------------------------------- small init
__global__ void init_kernel(int* counts, float* sums) {
  int t = threadIdx.x;
  if (t < E) counts[t] = 0;
  if (t < 16) sums[t] = 0.f;
}

// --------------------------------------------------------------- rmsnorm(x)
// xt = x * rsqrt(mean(x^2)+EPS); rs2[n] makes xs = xt*rs2 (second rmsnorm)
__global__ void rmsnorm_kernel(const float* __restrict__ x,
                               float* __restrict__ xt,
                               float* __restrict__ rs2) {
  int n = blockIdx.x;
  int tid = threadIdx.x;                          // 256 threads, 1 float4 each
  float4 v = ((const float4*)(x + (size_t)n * C))[tid];
  float ss = v.x*v.x + v.y*v.y + v.z*v.z + v.w*v.w;
  #pragma unroll
  for (int off = 32; off > 0; off >>= 1) ss += __shfl_down(ss, off, 64);
  __shared__ float red[4];
  __shared__ float tot;
  int wave = tid >> 6, lane = tid & 63;
  if (lane == 0) red[wave] = ss;
  __syncthreads();
  if (tid == 0) tot = red[0] + red[1] + red[2] + red[3];
  __syncthreads();
  float sumsq = tot;
  float rs1 = rsqrtf(sumsq * (1.f / C) + EPS);
  float4 o = make_float4(v.x*rs1, v.y*rs1, v.z*rs1, v.w*rs1);
  ((float4*)(xt + (size_t)n * C))[tid] = o;
  if (tid == 0) {
    // sum(xt^2) = rs1^2 * sum(x^2) exactly
    float m2 = sumsq * rs1 * rs1 * (1.f / C);
    rs2[n] = rsqrtf(m2 + EPS);
  }
}

// ------------------------------------------------------------------- gating
// raw[e]=xt·gate_w[e] (e<8), raw[8]=xt·shared_gate_w. softmax, top-2, lists.
__global__ void gate_kernel(const float* __restrict__ xt,
                            const float* __restrict__ gate_w,
                            const float* __restrict__ sgw,
                            float* __restrict__ g, float* __restrict__ sgbuf,
                            int* __restrict__ counts, int* __restrict__ lists,
                            float* __restrict__ sums) {
  int n = blockIdx.x;
  int tid = threadIdx.x;  // 256
  float acc[9];
  #pragma unroll
  for (int e = 0; e < 9; e++) acc[e] = 0.f;
  const float* xr = xt + (size_t)n * C;
  for (int c = tid; c < C; c += 256) {
    float xv = xr[c];
    #pragma unroll
    for (int e = 0; e < 8; e++) acc[e] = fmaf(xv, gate_w[e * C + c], acc[e]);
    acc[8] = fmaf(xv, sgw[c], acc[8]);
  }
  __shared__ float red[9][4];
  int wave = tid >> 6, lane = tid & 63;
  #pragma unroll
  for (int e = 0; e < 9; e++) {
    float v = acc[e];
    #pragma unroll
    for (int off = 32; off > 0; off >>= 1) v += __shfl_down(v, off, 64);
    if (lane == 0) red[e][wave] = v;
  }
  __syncthreads();
  if (tid == 0) {
    float raw[9];
    #pragma unroll
    for (int e = 0; e < 9; e++)
      raw[e] = red[e][0] + red[e][1] + red[e][2] + red[e][3];
    float m = raw[0];
    for (int e = 1; e < 8; e++) m = fmaxf(m, raw[e]);
    float sc[8], s = 0.f;
    for (int e = 0; e < 8; e++) { sc[e] = expf(raw[e] - m); s += sc[e]; }
    float inv = 1.f / s;
    for (int e = 0; e < 8; e++) sc[e] *= inv;
    int i1 = 0;
    for (int e = 1; e < 8; e++) if (sc[e] > sc[i1]) i1 = e;
    int i2 = -1;
    for (int e = 0; e < 8; e++) {
      if (e == i1) continue;
      if (i2 < 0 || sc[e] > sc[i2]) i2 = e;
    }
    float denom = sc[i1] + sc[i2] + 1e-6f;
    float* gr = g + (size_t)n * E;
    #pragma unroll
    for (int e = 0; e < 8; e++) gr[e] = 0.f;
    gr[i1] = sc[i1] / denom;
    gr[i2] = sc[i2] / denom;
    sgbuf[n] = 1.f / (1.f + expf(-raw[8]));
    for (int e = 0; e < 8; e++) atomicAdd(&sums[e], sc[e]);
    atomicAdd(&sums[8 + i1], 0.5f);
    atomicAdd(&sums[8 + i2], 0.5f);
    int p1 = atomicAdd(&counts[i1], 1); lists[i1 * N + p1] = (n << 1);
    int p2 = atomicAdd(&counts[i2], 1); lists[i2 * N + p2] = (n << 1) | 1;
  }
}

#define GEMM_COMPUTE_CHUNK                                         \
  _Pragma("unroll")                                                \
  for (int kk = 0; kk < KC; kk++) {                                \
    float4 a4 = *(const float4*)&As[kk][ty * 4];                   \
    float4 b4 = *(const float4*)&Bs[kk][tx * 4];                   \
    float av[4] = {a4.x, a4.y, a4.z, a4.w};                        \
    float bv[4] = {b4.x, b4.y, b4.z, b4.w};                        \
    _Pragma("unroll")                                              \
    for (int i = 0; i < 4; i++)                                    \
      _Pragma("unroll")                                            \
      for (int j = 0; j < 4; j++)                                  \
        acc[i][j] = fmaf(av[i], bv[j], acc[i][j]);                 \
  }

// -------------------------------------------- expert up-proj (gathered GEMM)
// h[row=(n<<1)|slot][h0+..] = relu(xt[n]·w1[e][h]ᵀ)^2 * g[n][e]
__global__ __launch_bounds__(256) void up_kernel(
    const float* __restrict__ xt, const float* __restrict__ w1,
    const float* __restrict__ g, const int* __restrict__ lists,
    const int* __restrict__ counts, float* __restrict__ hbuf) {
  const int e = blockIdx.y;
  const int cnt = counts[e];
  const int m0 = blockIdx.x * MT;
  if (m0 >= cnt) return;
  const int h0 = blockIdx.z * NTT;
  const int tid = threadIdx.x;
  __shared__ __align__(16) float As[KC][LDT];
  __shared__ __align__(16) float Bs[KC][LDT];
  __shared__ int toks[MT];
  if (tid < MT) toks[tid] = lists[e * N + min(m0 + tid, cnt - 1)];
  __syncthreads();
  const int tx = tid & 15, ty = tid >> 4;
  const int lc = tid & 15, lm = tid >> 4;
  float acc[4][4] = {};
  const float* wb = w1 + (size_t)e * H * C;
  for (int k0 = 0; k0 < C; k0 += KC) {
    #pragma unroll
    for (int i = 0; i < 4; i++) {
      int m = lm + 16 * i;
      As[lc][m] = xt[(size_t)(toks[m] >> 1) * C + k0 + lc];
      Bs[lc][m] = wb[(size_t)(h0 + m) * C + k0 + lc];
    }
    __syncthreads();
    GEMM_COMPUTE_CHUNK
    __syncthreads();
  }
  #pragma unroll
  for (int i = 0; i < 4; i++) {
    int m = ty * 4 + i;
    if (m0 + m < cnt) {
      int packed = toks[m];
      float gv = g[(size_t)(packed >> 1) * E + e];
      float* hr = hbuf + (size_t)packed * H + h0 + tx * 4;
      #pragma unroll
      for (int j = 0; j < 4; j++) {
        float v = fmaxf(acc[i][j], 0.f);
        hr[j] = v * v * gv;
      }
    }
  }
}

// ------------------------------------------ expert down-proj (gathered GEMM)
// out[n][c] += h[row]·w2[e][c]ᵀ  (atomic scatter; 2 experts/token)
__global__ __launch_bounds__(256) void down_kernel(
    const float* __restrict__ hbuf, const float* __restrict__ w2,
    const int* __restrict__ lists, const int* __restrict__ counts,
    float* __restrict__ out) {
  const int e = blockIdx.y;
  const int cnt = counts[e];
  const int m0 = blockIdx.x * MT;
  if (m0 >= cnt) return;
  const int c0 = blockIdx.z * NTT;
  const int tid = threadIdx.x;
  __shared__ __align__(16) float As[KC][LDT];
  __shared__ __align__(16) float Bs[KC][LDT];
  __shared__ int toks[MT];
  if (tid < MT) toks[tid] = lists[e * N + min(m0 + tid, cnt - 1)];
  __syncthreads();
  const int tx = tid & 15, ty = tid >> 4;
  const int lc = tid & 15, lm = tid >> 4;
  float acc[4][4] = {};
  const float* wb = w2 + (size_t)e * C * H;
  for (int k0 = 0; k0 < H; k0 += KC) {
    #pragma unroll
    for (int i = 0; i < 4; i++) {
      int m = lm + 16 * i;
      As[lc][m] = hbuf[(size_t)toks[m] * H + k0 + lc];
      Bs[lc][m] = wb[(size_t)(c0 + m) * H + k0 + lc];
    }
    __syncthreads();
    GEMM_COMPUTE_CHUNK
    __syncthreads();
  }
  #pragma unroll
  for (int i = 0; i < 4; i++) {
    int m = ty * 4 + i;
    if (m0 + m < cnt) {
      int tok = toks[m] >> 1;
      float* orow = out + (size_t)tok * C + c0 + tx * 4;
      #pragma unroll
      for (int j = 0; j < 4; j++) atomicAdd(&orow[j], acc[i][j]);
    }
  }
}

// --------------------------------------------------- shared expert: k-proj
// kk[n][h] = relu(rs2[n]*(xt[n]·k_w[h]ᵀ) + k_b[h])^2
__global__ __launch_bounds__(256) void kproj_kernel(
    const float* __restrict__ xt, const float* __restrict__ rs2,
    const float* __restrict__ k_w, const float* __restrict__ k_b,
    float* __restrict__ kk) {
  const int n0 = blockIdx.x * MT;
  const int h0 = blockIdx.y * NTT;
  const int tid = threadIdx.x;
  __shared__ __align__(16) float As[KC][LDT];
  __shared__ __align__(16) float Bs[KC][LDT];
  const int tx = tid & 15, ty = tid >> 4;
  const int lc = tid & 15, lm = tid >> 4;
  float acc[4][4] = {};
  for (int k0 = 0; k0 < C; k0 += KC) {
    #pragma unroll
    for (int i = 0; i < 4; i++) {
      int m = lm + 16 * i;
      As[lc][m] = xt[(size_t)(n0 + m) * C + k0 + lc];
      Bs[lc][m] = k_w[(size_t)(h0 + m) * C + k0 + lc];
    }
    __syncthreads();
    GEMM_COMPUTE_CHUNK
    __syncthreads();
  }
  #pragma unroll
  for (int i = 0; i < 4; i++) {
    int n = n0 + ty * 4 + i;
    float r = rs2[n];
    #pragma unroll
    for (int j = 0; j < 4; j++) {
      int h = h0 + tx * 4 + j;
      float v = fmaf(acc[i][j], r, k_b[h]);
      v = fmaxf(v, 0.f);
      kk[(size_t)n * H + h] = v * v;
    }
  }
}

// --------------------------------------------------- shared expert: v-proj
// out[n][c] += sg[n] * (kk[n]·v_w[c]ᵀ + v_b[c])   (reads moe-accumulated out)
__global__ __launch_bounds__(256) void vproj_kernel(
    const float* __restrict__ kk, const float* __restrict__ v_w,
    const float* __restrict__ v_b, const float* __restrict__ sg,
    float* __restrict__ out) {
  const int n0 = blockIdx.x * MT;
  const int c0 = blockIdx.y * NTT;
  const int tid = threadIdx.x;
  __shared__ __align__(16) float As[KC][LDT];
  __shared__ __align__(16) float Bs[KC][LDT];
  const int tx = tid & 15, ty = tid >> 4;
  const int lc = tid & 15, lm = tid >> 4;
  float acc[4][4] = {};
  for (int k0 = 0; k0 < H; k0 += KC) {
    #pragma unroll
    for (int i = 0; i < 4; i++) {
      int m = lm + 16 * i;
      As[lc][m] = kk[(size_t)(n0 + m) * H + k0 + lc];
      Bs[lc][m] = v_w[(size_t)(c0 + m) * H + k0 + lc];
    }
    __syncthreads();
    GEMM_COMPUTE_CHUNK
    __syncthreads();
  }
  #pragma unroll
  for (int i = 0; i < 4; i++) {
    int n = n0 + ty * 4 + i;
    float sgv = sg[n];
    #pragma unroll
    for (int j = 0; j < 4; j++) {
      int c = c0 + tx * 4 + j;
      size_t o = (size_t)n * C + c;
      out[o] = out[o] + sgv * (acc[i][j] + v_b[c]);
    }
  }
}

// -------------------------------------------------------------------- aux
__global__ void aux_kernel(const float* __restrict__ sums,
                           float* __restrict__ out_aux) {
  if (threadIdx.x == 0) {
    float a = 0.f;
    for (int e = 0; e < 8; e++)
      a += (sums[8 + e] * (1.f / N)) * (sums[e] * (1.f / N));
    out_aux[0] = 8.f * a * 0.01f;
  }
}

extern "C" void kernel_launch(void* const* d_in, const int* in_sizes, int n_in,
                              void* d_out, int out_size, void* d_ws, size_t ws_size,
                              hipStream_t stream) {
  (void)in_sizes; (void)n_in; (void)ws_size;
  const float* x   = (const float*)d_in[0];
  const float* gw  = (const float*)d_in[1];
  const float* w1  = (const float*)d_in[2];
  const float* w2  = (const float*)d_in[3];
  const float* sgw = (const float*)d_in[4];
  const float* k_w = (const float*)d_in[5];
  const float* k_b = (const float*)d_in[6];
  const float* v_w = (const float*)d_in[7];
  const float* v_b = (const float*)d_in[8];
  float* out = (float*)d_out;

  // workspace layout (~40.1 MiB)
  float* ws     = (float*)d_ws;
  float* xt     = ws;                         // N*C
  float* rs2    = xt + (size_t)N * C;         // N
  float* g      = rs2 + N;                    // N*E
  float* sg     = g + (size_t)N * E;          // N
  float* sums   = sg + N;                     // 16 (scores 0..7, onehot 8..15)
  int*   counts = (int*)(sums + 16);          // E
  int*   lists  = counts + 8;                 // E*N packed (n<<1)|slot
  float* hbuf   = (float*)(lists + (size_t)E * N);  // 2N*H
  float* kkbuf  = hbuf;  // alias: down reads hbuf strictly before kproj writes

  hipMemsetAsync(d_out, 0, (size_t)out_size * sizeof(float), stream);
  init_kernel<<<1, 32, 0, stream>>>(counts, sums);
  rmsnorm_kernel<<<N, 256, 0, stream>>>(x, xt, rs2);
  gate_kernel<<<N, 256, 0, stream>>>(xt, gw, sgw, g, sg, counts, lists, sums);
  up_kernel<<<dim3(N / MT, E, H / NTT), 256, 0, stream>>>(xt, w1, g, lists, counts, hbuf);
  down_kernel<<<dim3(N / MT, E, C / NTT), 256, 0, stream>>>(hbuf, w2, lists, counts, out);
  kproj_kernel<<<dim3(N / MT, H / NTT), 256, 0, stream>>>(xt, rs2, k_w, k_b, kkbuf);
  vproj_kernel<<<dim3(N / MT, C / NTT), 256, 0, stream>>>(kkbuf, v_w, v_b, sg, out);
  aux_kernel<<<1, 64, 0, stream>>>(sums, out + (size_t)N * C);
}

// Round 2
// 705.050 us; speedup vs baseline: 3.0113x; 3.0113x over previous
//
#include <hip/hip_runtime.h>
#include <hip/hip_bf16.h>
#include <stdint.h>

typedef __bf16 bf16;
typedef bf16 bf16x8 __attribute__((ext_vector_type(8)));
typedef bf16 bf16x4 __attribute__((ext_vector_type(4)));
typedef float f32x4 __attribute__((ext_vector_type(4)));

constexpr int N = 2048;   // tokens
constexpr int C = 1024;   // model dim
constexpr int H = 2048;   // hidden dim
constexpr int E = 8;      // experts
constexpr float EPS = 1.1920929e-07f;

constexpr int BM = 128, BN = 128, BK = 32;   // bf16 MFMA tile (m97 structure)

// ---------------------------------------------------------------- small init
__global__ void init_kernel(int* counts, float* sums) {
  int t = threadIdx.x;
  if (t < E) counts[t] = 0;
  if (t < 16) sums[t] = 0.f;
}

// ----------------------------------------------------------- fp32 -> bf16 cvt
__global__ void cvt_kernel(const float* __restrict__ src, bf16* __restrict__ dst) {
  int i = blockIdx.x * 256 + threadIdx.x;     // one float4 per thread, exact grid
  float4 v = ((const float4*)src)[i];
  bf16x4 o = { (bf16)v.x, (bf16)v.y, (bf16)v.z, (bf16)v.w };
  ((bf16x4*)dst)[i] = o;
}

// --------------------------------------------------------------- rmsnorm(x)
// xtb = bf16(x * rs1); rs1 = rsqrt(mean(x^2)+EPS); rs2 for second rmsnorm
__global__ void rmsnorm_kernel(const float* __restrict__ x,
                               bf16* __restrict__ xtb,
                               float* __restrict__ rs1_arr,
                               float* __restrict__ rs2_arr) {
  int n = blockIdx.x;
  int tid = threadIdx.x;                      // 256 threads, 1 float4 each
  float4 v = ((const float4*)(x + (size_t)n * C))[tid];
  float ss = v.x*v.x + v.y*v.y + v.z*v.z + v.w*v.w;
  #pragma unroll
  for (int off = 32; off > 0; off >>= 1) ss += __shfl_down(ss, off, 64);
  __shared__ float red[4];
  __shared__ float tot;
  int wave = tid >> 6, lane = tid & 63;
  if (lane == 0) red[wave] = ss;
  __syncthreads();
  if (tid == 0) tot = red[0] + red[1] + red[2] + red[3];
  __syncthreads();
  float sumsq = tot;
  float rs1 = rsqrtf(sumsq * (1.f / C) + EPS);
  bf16x4 o = { (bf16)(v.x*rs1), (bf16)(v.y*rs1), (bf16)(v.z*rs1), (bf16)(v.w*rs1) };
  ((bf16x4*)(xtb + (size_t)n * C))[tid] = o;
  if (tid == 0) {
    rs1_arr[n] = rs1;
    float m2 = sumsq * rs1 * rs1 * (1.f / C);  // mean(xt^2) exactly
    rs2_arr[n] = rsqrtf(m2 + EPS);
  }
}

// ------------------------------------------------------------------- gating
// fp32 path (bf16 logits could flip near-tie top-2). raw = rs1 * (x . w)
__global__ void gate_kernel(const float* __restrict__ x,
                            const float* __restrict__ rs1_arr,
                            const float* __restrict__ gate_w,
                            const float* __restrict__ sgw,
                            float* __restrict__ g, float* __restrict__ sgbuf,
                            int* __restrict__ counts, int* __restrict__ lists,
                            float* __restrict__ sums) {
  int n = blockIdx.x;
  int tid = threadIdx.x;  // 256
  float acc[9];
  #pragma unroll
  for (int e = 0; e < 9; e++) acc[e] = 0.f;
  const float* xr = x + (size_t)n * C;
  for (int c = tid; c < C; c += 256) {
    float xv = xr[c];
    #pragma unroll
    for (int e = 0; e < 8; e++) acc[e] = fmaf(xv, gate_w[e * C + c], acc[e]);
    acc[8] = fmaf(xv, sgw[c], acc[8]);
  }
  __shared__ float red[9][4];
  int wave = tid >> 6, lane = tid & 63;
  #pragma unroll
  for (int e = 0; e < 9; e++) {
    float v = acc[e];
    #pragma unroll
    for (int off = 32; off > 0; off >>= 1) v += __shfl_down(v, off, 64);
    if (lane == 0) red[e][wave] = v;
  }
  __syncthreads();
  if (tid == 0) {
    float rs1 = rs1_arr[n];
    float raw[9];
    #pragma unroll
    for (int e = 0; e < 9; e++)
      raw[e] = (red[e][0] + red[e][1] + red[e][2] + red[e][3]) * rs1;
    float m = raw[0];
    for (int e = 1; e < 8; e++) m = fmaxf(m, raw[e]);
    float sc[8], s = 0.f;
    for (int e = 0; e < 8; e++) { sc[e] = expf(raw[e] - m); s += sc[e]; }
    float inv = 1.f / s;
    for (int e = 0; e < 8; e++) sc[e] *= inv;
    int i1 = 0;
    for (int e = 1; e < 8; e++) if (sc[e] > sc[i1]) i1 = e;
    int i2 = -1;
    for (int e = 0; e < 8; e++) {
      if (e == i1) continue;
      if (i2 < 0 || sc[e] > sc[i2]) i2 = e;
    }
    float denom = sc[i1] + sc[i2] + 1e-6f;
    float* gr = g + (size_t)n * E;
    #pragma unroll
    for (int e = 0; e < 8; e++) gr[e] = 0.f;
    gr[i1] = sc[i1] / denom;
    gr[i2] = sc[i2] / denom;
    sgbuf[n] = 1.f / (1.f + expf(-raw[8]));
    for (int e = 0; e < 8; e++) atomicAdd(&sums[e], sc[e]);
    atomicAdd(&sums[8 + i1], 0.5f);
    atomicAdd(&sums[8 + i2], 0.5f);
    int p1 = atomicAdd(&counts[i1], 1); lists[i1 * N + p1] = (n << 1);
    int p2 = atomicAdd(&counts[i2], 1); lists[i2 * N + p2] = (n << 1) | 1;
  }
}

// -------------------------------------------------------- MFMA GEMM mainloop
// m97 structure: 128x128 tile, BK=32, 4 waves 2x2, global_load_lds width=16.
// LDS tiles: row-major [128][32] bf16 (64B rows, no pad). Fragment reads are
// conflict-free (8 distinct b128 addrs/wave covering all 32 banks).
__device__ __forceinline__ void mfma_loop(
    const char* gA0, const char* gA1, const char* gB0, const char* gB1,
    char* As, char* Bs, int wave, int lane, int kIters,
    int mb, int nb, f32x4 acc[4][4]) {
  const int l0 = wave * 2048, l1 = l0 + 1024;   // wave-uniform LDS bases
  const int arow = lane & 15;
  const int koff = (lane >> 4) * 16;            // quad*8 elems * 2B
  for (int kt = 0; kt < kIters; ++kt) {
    __builtin_amdgcn_global_load_lds((__attribute__((address_space(1))) void*)gA0,
                                     (__attribute__((address_space(3))) void*)(As + l0), 16, 0, 0);
    __builtin_amdgcn_global_load_lds((__attribute__((address_space(1))) void*)gA1,
                                     (__attribute__((address_space(3))) void*)(As + l1), 16, 0, 0);
    __builtin_amdgcn_global_load_lds((__attribute__((address_space(1))) void*)gB0,
                                     (__attribute__((address_space(3))) void*)(Bs + l0), 16, 0, 0);
    __builtin_amdgcn_global_load_lds((__attribute__((address_space(1))) void*)gB1,
                                     (__attribute__((address_space(3))) void*)(Bs + l1), 16, 0, 0);
    gA0 += BK * 2; gA1 += BK * 2; gB0 += BK * 2; gB1 += BK * 2;
    __syncthreads();
    bf16x8 a[4], b[4];
    #pragma unroll
    for (int i = 0; i < 4; ++i) {
      a[i] = *(const bf16x8*)(As + (mb + i * 16 + arow) * 64 + koff);
      b[i] = *(const bf16x8*)(Bs + (nb + i * 16 + arow) * 64 + koff);
    }
    #pragma unroll
    for (int i = 0; i < 4; ++i)
      #pragma unroll
      for (int j = 0; j < 4; ++j)
        acc[i][j] = __builtin_amdgcn_mfma_f32_16x16x32_bf16(a[i], b[j], acc[i][j], 0, 0, 0);
    __syncthreads();
  }
}

#define GEMM_PROLOGUE                                              \
  const int tid = threadIdx.x;                                     \
  const int lane = tid & 63, wave = tid >> 6;                      \
  const int sr0 = wave * 32 + (lane >> 2), sr1 = sr0 + 16;         \
  const int scb = (lane & 3) * 16; /* staging col bytes */         \
  const int mb = (wave & 1) * 64, nb = (wave >> 1) * 64;           \
  const int col = lane & 15, quad = lane >> 4;                     \
  __shared__ __align__(16) char As[BM * BK * 2];                   \
  __shared__ __align__(16) char Bs[BN * BK * 2];                   \
  f32x4 acc[4][4] = {};

// -------------------------------------------- expert up-proj (gathered GEMM)
__global__ void up_kernel(const bf16* __restrict__ xtb, const bf16* __restrict__ w1b,
                          const float* __restrict__ g, const int* __restrict__ lists,
                          const int* __restrict__ counts, bf16* __restrict__ hb) {
  const int e = blockIdx.y;
  const int cnt = counts[e];
  const int m0 = blockIdx.x * BM;
  if (m0 >= cnt) return;
  const int h0 = blockIdx.z * BN;
  GEMM_PROLOGUE
  __shared__ int toks[BM];
  if (tid < BM) toks[tid] = lists[e * N + min(m0 + tid, cnt - 1)];
  __syncthreads();
  const char* gA0 = (const char*)xtb + ((size_t)(toks[sr0] >> 1) * C) * 2 + scb;
  const char* gA1 = (const char*)xtb + ((size_t)(toks[sr1] >> 1) * C) * 2 + scb;
  const char* gB0 = (const char*)w1b + ((size_t)e * H * C + (size_t)(h0 + sr0) * C) * 2 + scb;
  const char* gB1 = (const char*)w1b + ((size_t)e * H * C + (size_t)(h0 + sr1) * C) * 2 + scb;
  mfma_loop(gA0, gA1, gB0, gB1, As, Bs, wave, lane, C / BK, mb, nb, acc);
  #pragma unroll
  for (int mi = 0; mi < 4; mi++) {
    #pragma unroll
    for (int r = 0; r < 4; r++) {
      int ml = mb + mi * 16 + quad * 4 + r;
      if (m0 + ml < cnt) {
        int packed = toks[ml];
        float gv = g[(size_t)(packed >> 1) * E + e];
        size_t base = (size_t)packed * H + h0 + nb;
        #pragma unroll
        for (int ni = 0; ni < 4; ni++) {
          float v = fmaxf(acc[mi][ni][r], 0.f);
          hb[base + ni * 16 + col] = (bf16)(v * v * gv);
        }
      }
    }
  }
}

// ------------------------------------------ expert down-proj (gathered GEMM)
__global__ void down_kernel(const bf16* __restrict__ hb, const bf16* __restrict__ w2b,
                            const int* __restrict__ lists, const int* __restrict__ counts,
                            float* __restrict__ out) {
  const int e = blockIdx.y;
  const int cnt = counts[e];
  const int m0 = blockIdx.x * BM;
  if (m0 >= cnt) return;
  const int c0 = blockIdx.z * BN;
  GEMM_PROLOGUE
  __shared__ int toks[BM];
  if (tid < BM) toks[tid] = lists[e * N + min(m0 + tid, cnt - 1)];
  __syncthreads();
  const char* gA0 = (const char*)hb + ((size_t)toks[sr0] * H) * 2 + scb;
  const char* gA1 = (const char*)hb + ((size_t)toks[sr1] * H) * 2 + scb;
  const char* gB0 = (const char*)w2b + ((size_t)e * C * H + (size_t)(c0 + sr0) * H) * 2 + scb;
  const char* gB1 = (const char*)w2b + ((size_t)e * C * H + (size_t)(c0 + sr1) * H) * 2 + scb;
  mfma_loop(gA0, gA1, gB0, gB1, As, Bs, wave, lane, H / BK, mb, nb, acc);
  #pragma unroll
  for (int mi = 0; mi < 4; mi++) {
    #pragma unroll
    for (int r = 0; r < 4; r++) {
      int ml = mb + mi * 16 + quad * 4 + r;
      if (m0 + ml < cnt) {
        int tok = toks[ml] >> 1;
        float* orow = out + (size_t)tok * C + c0 + nb;
        #pragma unroll
        for (int ni = 0; ni < 4; ni++) atomicAdd(&orow[ni * 16 + col], acc[mi][ni][r]);
      }
    }
  }
}

// --------------------------------------------------- shared expert: k-proj
// kk = bf16( relu(rs2*(xt.k_w^T) + k_b)^2 )
__global__ void kproj_kernel(const bf16* __restrict__ xtb, const bf16* __restrict__ kwb,
                             const float* __restrict__ rs2, const float* __restrict__ k_b,
                             bf16* __restrict__ kkb) {
  const int n0 = blockIdx.x * BM;
  const int h0 = blockIdx.y * BN;
  GEMM_PROLOGUE
  const char* gA0 = (const char*)xtb + ((size_t)(n0 + sr0) * C) * 2 + scb;
  const char* gA1 = (const char*)xtb + ((size_t)(n0 + sr1) * C) * 2 + scb;
  const char* gB0 = (const char*)kwb + ((size_t)(h0 + sr0) * C) * 2 + scb;
  const char* gB1 = (const char*)kwb + ((size_t)(h0 + sr1) * C) * 2 + scb;
  mfma_loop(gA0, gA1, gB0, gB1, As, Bs, wave, lane, C / BK, mb, nb, acc);
  #pragma unroll
  for (int mi = 0; mi < 4; mi++) {
    #pragma unroll
    for (int r = 0; r < 4; r++) {
      int n = n0 + mb + mi * 16 + quad * 4 + r;
      float rs = rs2[n];
      #pragma unroll
      for (int ni = 0; ni < 4; ni++) {
        int h = h0 + nb + ni * 16 + col;
        float v = fmaf(acc[mi][ni][r], rs, k_b[h]);
        v = fmaxf(v, 0.f);
        kkb[(size_t)n * H + h] = (bf16)(v * v);
      }
    }
  }
}

// --------------------------------------------------- shared expert: v-proj
// out += sg * (kk.v_w^T + v_b)   (out already holds routed sum)
__global__ void vproj_kernel(const bf16* __restrict__ kkb, const bf16* __restrict__ vwb,
                             const float* __restrict__ v_b, const float* __restrict__ sg,
                             float* __restrict__ out) {
  const int n0 = blockIdx.x * BM;
  const int c0 = blockIdx.y * BN;
  GEMM_PROLOGUE
  const char* gA0 = (const char*)kkb + ((size_t)(n0 + sr0) * H) * 2 + scb;
  const char* gA1 = (const char*)kkb + ((size_t)(n0 + sr1) * H) * 2 + scb;
  const char* gB0 = (const char*)vwb + ((size_t)(c0 + sr0) * H) * 2 + scb;
  const char* gB1 = (const char*)vwb + ((size_t)(c0 + sr1) * H) * 2 + scb;
  mfma_loop(gA0, gA1, gB0, gB1, As, Bs, wave, lane, H / BK, mb, nb, acc);
  #pragma unroll
  for (int mi = 0; mi < 4; mi++) {
    #pragma unroll
    for (int r = 0; r < 4; r++) {
      int n = n0 + mb + mi * 16 + quad * 4 + r;
      float sgv = sg[n];
      #pragma unroll
      for (int ni = 0; ni < 4; ni++) {
        int c = c0 + nb + ni * 16 + col;
        size_t o = (size_t)n * C + c;
        out[o] = out[o] + sgv * (acc[mi][ni][r] + v_b[c]);
      }
    }
  }
}

// -------------------------------------------------------------------- aux
__global__ void aux_kernel(const float* __restrict__ sums,
                           float* __restrict__ out_aux) {
  if (threadIdx.x == 0) {
    float a = 0.f;
    for (int e = 0; e < 8; e++)
      a += (sums[8 + e] * (1.f / N)) * (sums[e] * (1.f / N));
    out_aux[0] = 8.f * a * 0.01f;
  }
}

extern "C" void kernel_launch(void* const* d_in, const int* in_sizes, int n_in,
                              void* d_out, int out_size, void* d_ws, size_t ws_size,
                              hipStream_t stream) {
  (void)in_sizes; (void)n_in; (void)ws_size;
  const float* x   = (const float*)d_in[0];
  const float* gw  = (const float*)d_in[1];
  const float* w1  = (const float*)d_in[2];
  const float* w2  = (const float*)d_in[3];
  const float* sgw = (const float*)d_in[4];
  const float* k_w = (const float*)d_in[5];
  const float* k_b = (const float*)d_in[6];
  const float* v_w = (const float*)d_in[7];
  const float* v_b = (const float*)d_in[8];
  float* out = (float*)d_out;

  // workspace layout (~97 MiB)
  char* p = (char*)d_ws;
  auto alloc = [&](size_t bytes) { char* r = p; p += (bytes + 255) & ~255ull; return r; };
  bf16* xtb  = (bf16*)alloc((size_t)N * C * 2);
  bf16* w1b  = (bf16*)alloc((size_t)E * H * C * 2);
  bf16* w2b  = (bf16*)alloc((size_t)E * C * H * 2);
  bf16* kwb  = (bf16*)alloc((size_t)H * C * 2);
  bf16* vwb  = (bf16*)alloc((size_t)C * H * 2);
  bf16* hb   = (bf16*)alloc((size_t)2 * N * H * 2);  // [2N][H], packed-slot rows
  bf16* kkb  = hb;  // alias: down reads hb strictly before kproj writes kkb
  float* rs1 = (float*)alloc((size_t)N * 4);
  float* rs2 = (float*)alloc((size_t)N * 4);
  float* g   = (float*)alloc((size_t)N * E * 4);
  float* sg  = (float*)alloc((size_t)N * 4);
  float* sums = (float*)alloc(64);
  int* counts = (int*)alloc(64);
  int* lists  = (int*)alloc((size_t)E * N * 4);

  hipMemsetAsync(d_out, 0, (size_t)out_size * sizeof(float), stream);
  init_kernel<<<1, 32, 0, stream>>>(counts, sums);
  // bf16 weight conversion (exact grids: counts divisible by 1024)
  cvt_kernel<<<(E * H * C) / 1024, 256, 0, stream>>>(w1, w1b);
  cvt_kernel<<<(E * C * H) / 1024, 256, 0, stream>>>(w2, w2b);
  cvt_kernel<<<(H * C) / 1024, 256, 0, stream>>>(k_w, kwb);
  cvt_kernel<<<(C * H) / 1024, 256, 0, stream>>>(v_w, vwb);
  rmsnorm_kernel<<<N, 256, 0, stream>>>(x, xtb, rs1, rs2);
  gate_kernel<<<N, 256, 0, stream>>>(x, rs1, gw, sgw, g, sg, counts, lists, sums);
  up_kernel<<<dim3(N / BM, E, H / BN), 256, 0, stream>>>(xtb, w1b, g, lists, counts, hb);
  down_kernel<<<dim3(N / BM, E, C / BN), 256, 0, stream>>>(hb, w2b, lists, counts, out);
  kproj_kernel<<<dim3(N / BM, H / BN), 256, 0, stream>>>(xtb, kwb, rs2, k_b, kkb);
  vproj_kernel<<<dim3(N / BM, C / BN), 256, 0, stream>>>(kkb, vwb, v_b, sg, out);
  aux_kernel<<<1, 64, 0, stream>>>(sums, out + (size_t)N * C);
}

// Round 3
// 475.264 us; speedup vs baseline: 4.4673x; 1.4835x over previous
//
#include <hip/hip_runtime.h>
#include <hip/hip_bf16.h>
#include <stdint.h>

typedef __bf16 bf16;
typedef bf16 bf16x8 __attribute__((ext_vector_type(8)));
typedef bf16 bf16x4 __attribute__((ext_vector_type(4)));
typedef float f32x4 __attribute__((ext_vector_type(4)));

constexpr int N = 2048;   // tokens
constexpr int C = 1024;   // model dim
constexpr int H = 2048;   // hidden dim
constexpr int E = 8;      // experts
constexpr float EPS = 1.1920929e-07f;

constexpr int BM = 128, BN = 128, BK = 32;   // bf16 MFMA tile (m97 structure)
constexpr int GT = 32;                       // tokens per gate block

// ---------------------------------------------------------------- small init
__global__ void init_kernel(int* counts, float* scoresums) {
  int t = threadIdx.x;
  if (t < E) counts[t] = 0;
  if (t < E) scoresums[t] = 0.f;
}

// ----------------------------------------------------------- fp32 -> bf16 cvt
__global__ void cvt_kernel(const float* __restrict__ src, bf16* __restrict__ dst) {
  int i = blockIdx.x * 256 + threadIdx.x;     // one float4 per thread, exact grid
  float4 v = ((const float4*)src)[i];
  bf16x4 o = { (bf16)v.x, (bf16)v.y, (bf16)v.z, (bf16)v.w };
  ((bf16x4*)dst)[i] = o;
}

// --------------------------------------------------------------- rmsnorm(x)
// xtb = bf16(x * rs1); rs1 = rsqrt(mean(x^2)+EPS); rs2 for second rmsnorm
__global__ void rmsnorm_kernel(const float* __restrict__ x,
                               bf16* __restrict__ xtb,
                               float* __restrict__ rs1_arr,
                               float* __restrict__ rs2_arr) {
  int n = blockIdx.x;
  int tid = threadIdx.x;                      // 256 threads, 1 float4 each
  float4 v = ((const float4*)(x + (size_t)n * C))[tid];
  float ss = v.x*v.x + v.y*v.y + v.z*v.z + v.w*v.w;
  #pragma unroll
  for (int off = 32; off > 0; off >>= 1) ss += __shfl_down(ss, off, 64);
  __shared__ float red[4];
  __shared__ float tot;
  int wave = tid >> 6, lane = tid & 63;
  if (lane == 0) red[wave] = ss;
  __syncthreads();
  if (tid == 0) tot = red[0] + red[1] + red[2] + red[3];
  __syncthreads();
  float sumsq = tot;
  float rs1 = rsqrtf(sumsq * (1.f / C) + EPS);
  bf16x4 o = { (bf16)(v.x*rs1), (bf16)(v.y*rs1), (bf16)(v.z*rs1), (bf16)(v.w*rs1) };
  ((bf16x4*)(xtb + (size_t)n * C))[tid] = o;
  if (tid == 0) {
    rs1_arr[n] = rs1;
    float m2 = sumsq * rs1 * rs1 * (1.f / C);  // mean(xt^2) exactly
    rs2_arr[n] = rsqrtf(m2 + EPS);
  }
}

// ------------------------------------------------------------------- gating
// Block-aggregated: 32 tokens/block, gate weights in LDS, per-block LDS
// reduction of counts/score-sums, ONE global atomic per expert per block.
// (Round-2 version: ~25K same-cache-line global atomics -> 277 us stall.)
__global__ __launch_bounds__(256) void gate_kernel(
    const float* __restrict__ x, const float* __restrict__ rs1_arr,
    const float* __restrict__ gate_w, const float* __restrict__ sgw,
    float* __restrict__ g, float* __restrict__ sgbuf,
    int* __restrict__ counts, int* __restrict__ lists,
    float* __restrict__ scoresums) {
  __shared__ float wsm[9][1024];   // 36 KB: 8 expert rows + shared-gate row
  __shared__ float s_scores[8];
  __shared__ int   s_cnt[8];
  __shared__ int   s_base[8];
  __shared__ int   s_e1[GT], s_p1[GT], s_e2[GT], s_p2[GT];
  const int tid = threadIdx.x, lane = tid & 63, wave = tid >> 6;
  for (int i = tid; i < 9 * 1024; i += 256) {
    int e = i >> 10, c = i & 1023;
    wsm[e][c] = (e < 8) ? gate_w[i] : sgw[c];
  }
  if (tid < 8) { s_scores[tid] = 0.f; s_cnt[tid] = 0; }
  __syncthreads();

  const int tok0 = blockIdx.x * GT + wave * (GT / 4);
  for (int tt = 0; tt < GT / 4; ++tt) {
    const int tok = tok0 + tt;
    const float* xr = x + (size_t)tok * C;
    float acc[9];
    #pragma unroll
    for (int e = 0; e < 9; e++) acc[e] = 0.f;
    #pragma unroll
    for (int k = 0; k < 16; ++k) {
      int c = k * 64 + lane;
      float xv = xr[c];
      #pragma unroll
      for (int e = 0; e < 9; e++) acc[e] = fmaf(xv, wsm[e][c], acc[e]);
    }
    #pragma unroll
    for (int e = 0; e < 9; e++) {
      float v = acc[e];
      #pragma unroll
      for (int off = 32; off > 0; off >>= 1) v += __shfl_xor(v, off, 64);
      acc[e] = v;
    }
    if (lane == 0) {
      float rs1 = rs1_arr[tok];
      float raw[9];
      #pragma unroll
      for (int e = 0; e < 9; e++) raw[e] = acc[e] * rs1;
      float m = raw[0];
      for (int e = 1; e < 8; e++) m = fmaxf(m, raw[e]);
      float sc[8], s = 0.f;
      for (int e = 0; e < 8; e++) { sc[e] = expf(raw[e] - m); s += sc[e]; }
      float inv = 1.f / s;
      for (int e = 0; e < 8; e++) sc[e] *= inv;
      int i1 = 0;
      for (int e = 1; e < 8; e++) if (sc[e] > sc[i1]) i1 = e;
      int i2 = -1;
      for (int e = 0; e < 8; e++) {
        if (e == i1) continue;
        if (i2 < 0 || sc[e] > sc[i2]) i2 = e;
      }
      float denom = sc[i1] + sc[i2] + 1e-6f;
      float* gr = g + (size_t)tok * E;
      #pragma unroll
      for (int e = 0; e < 8; e++) gr[e] = 0.f;
      gr[i1] = sc[i1] / denom;
      gr[i2] = sc[i2] / denom;
      sgbuf[tok] = 1.f / (1.f + expf(-raw[8]));
      for (int e = 0; e < 8; e++) atomicAdd(&s_scores[e], sc[e]);  // LDS
      int lt = wave * (GT / 4) + tt;
      int p1 = atomicAdd(&s_cnt[i1], 1);   // LDS
      int p2 = atomicAdd(&s_cnt[i2], 1);   // LDS
      s_e1[lt] = i1; s_p1[lt] = p1;
      s_e2[lt] = i2; s_p2[lt] = p2;
    }
  }
  __syncthreads();
  if (tid < 8) {
    s_base[tid] = atomicAdd(&counts[tid], s_cnt[tid]);   // 8 global atomics
    atomicAdd(&scoresums[tid], s_scores[tid]);           // 8 global atomics
  }
  __syncthreads();
  if (tid < GT) {
    int tok = blockIdx.x * GT + tid;
    int e1 = s_e1[tid], e2 = s_e2[tid];
    lists[e1 * N + s_base[e1] + s_p1[tid]] = (tok << 1);
    lists[e2 * N + s_base[e2] + s_p2[tid]] = (tok << 1) | 1;
  }
}

// -------------------------------------------------------- MFMA GEMM mainloop
// m97 structure: 128x128 tile, BK=32, 4 waves 2x2, global_load_lds width=16.
// LDS tiles: row-major [128][32] bf16 (64B rows, no pad). Fragment reads are
// conflict-free (8 distinct b128 addrs/wave covering all 32 banks).
__device__ __forceinline__ void mfma_loop(
    const char* gA0, const char* gA1, const char* gB0, const char* gB1,
    char* As, char* Bs, int wave, int lane, int kIters,
    int mb, int nb, f32x4 acc[4][4]) {
  const int l0 = wave * 2048, l1 = l0 + 1024;   // wave-uniform LDS bases
  const int arow = lane & 15;
  const int koff = (lane >> 4) * 16;            // quad*8 elems * 2B
  for (int kt = 0; kt < kIters; ++kt) {
    __builtin_amdgcn_global_load_lds((__attribute__((address_space(1))) void*)gA0,
                                     (__attribute__((address_space(3))) void*)(As + l0), 16, 0, 0);
    __builtin_amdgcn_global_load_lds((__attribute__((address_space(1))) void*)gA1,
                                     (__attribute__((address_space(3))) void*)(As + l1), 16, 0, 0);
    __builtin_amdgcn_global_load_lds((__attribute__((address_space(1))) void*)gB0,
                                     (__attribute__((address_space(3))) void*)(Bs + l0), 16, 0, 0);
    __builtin_amdgcn_global_load_lds((__attribute__((address_space(1))) void*)gB1,
                                     (__attribute__((address_space(3))) void*)(Bs + l1), 16, 0, 0);
    gA0 += BK * 2; gA1 += BK * 2; gB0 += BK * 2; gB1 += BK * 2;
    __syncthreads();
    bf16x8 a[4], b[4];
    #pragma unroll
    for (int i = 0; i < 4; ++i) {
      a[i] = *(const bf16x8*)(As + (mb + i * 16 + arow) * 64 + koff);
      b[i] = *(const bf16x8*)(Bs + (nb + i * 16 + arow) * 64 + koff);
    }
    #pragma unroll
    for (int i = 0; i < 4; ++i)
      #pragma unroll
      for (int j = 0; j < 4; ++j)
        acc[i][j] = __builtin_amdgcn_mfma_f32_16x16x32_bf16(a[i], b[j], acc[i][j], 0, 0, 0);
    __syncthreads();
  }
}

#define GEMM_PROLOGUE                                              \
  const int tid = threadIdx.x;                                     \
  const int lane = tid & 63, wave = tid >> 6;                      \
  const int sr0 = wave * 32 + (lane >> 2), sr1 = sr0 + 16;         \
  const int scb = (lane & 3) * 16; /* staging col bytes */         \
  const int mb = (wave & 1) * 64, nb = (wave >> 1) * 64;           \
  const int col = lane & 15, quad = lane >> 4;                     \
  __shared__ __align__(16) char As[BM * BK * 2];                   \
  __shared__ __align__(16) char Bs[BN * BK * 2];                   \
  f32x4 acc[4][4] = {};

// -------------------------------------------- expert up-proj (gathered GEMM)
__global__ void up_kernel(const bf16* __restrict__ xtb, const bf16* __restrict__ w1b,
                          const float* __restrict__ g, const int* __restrict__ lists,
                          const int* __restrict__ counts, bf16* __restrict__ hb) {
  const int e = blockIdx.y;
  const int cnt = counts[e];
  const int m0 = blockIdx.x * BM;
  if (m0 >= cnt) return;
  const int h0 = blockIdx.z * BN;
  GEMM_PROLOGUE
  __shared__ int toks[BM];
  if (tid < BM) toks[tid] = lists[e * N + min(m0 + tid, cnt - 1)];
  __syncthreads();
  const char* gA0 = (const char*)xtb + ((size_t)(toks[sr0] >> 1) * C) * 2 + scb;
  const char* gA1 = (const char*)xtb + ((size_t)(toks[sr1] >> 1) * C) * 2 + scb;
  const char* gB0 = (const char*)w1b + ((size_t)e * H * C + (size_t)(h0 + sr0) * C) * 2 + scb;
  const char* gB1 = (const char*)w1b + ((size_t)e * H * C + (size_t)(h0 + sr1) * C) * 2 + scb;
  mfma_loop(gA0, gA1, gB0, gB1, As, Bs, wave, lane, C / BK, mb, nb, acc);
  #pragma unroll
  for (int mi = 0; mi < 4; mi++) {
    #pragma unroll
    for (int r = 0; r < 4; r++) {
      int ml = mb + mi * 16 + quad * 4 + r;
      if (m0 + ml < cnt) {
        int packed = toks[ml];
        float gv = g[(size_t)(packed >> 1) * E + e];
        size_t base = (size_t)packed * H + h0 + nb;
        #pragma unroll
        for (int ni = 0; ni < 4; ni++) {
          float v = fmaxf(acc[mi][ni][r], 0.f);
          hb[base + ni * 16 + col] = (bf16)(v * v * gv);
        }
      }
    }
  }
}

// ------------------------------------------ expert down-proj (gathered GEMM)
__global__ void down_kernel(const bf16* __restrict__ hb, const bf16* __restrict__ w2b,
                            const int* __restrict__ lists, const int* __restrict__ counts,
                            float* __restrict__ out) {
  const int e = blockIdx.y;
  const int cnt = counts[e];
  const int m0 = blockIdx.x * BM;
  if (m0 >= cnt) return;
  const int c0 = blockIdx.z * BN;
  GEMM_PROLOGUE
  __shared__ int toks[BM];
  if (tid < BM) toks[tid] = lists[e * N + min(m0 + tid, cnt - 1)];
  __syncthreads();
  const char* gA0 = (const char*)hb + ((size_t)toks[sr0] * H) * 2 + scb;
  const char* gA1 = (const char*)hb + ((size_t)toks[sr1] * H) * 2 + scb;
  const char* gB0 = (const char*)w2b + ((size_t)e * C * H + (size_t)(c0 + sr0) * H) * 2 + scb;
  const char* gB1 = (const char*)w2b + ((size_t)e * C * H + (size_t)(c0 + sr1) * H) * 2 + scb;
  mfma_loop(gA0, gA1, gB0, gB1, As, Bs, wave, lane, H / BK, mb, nb, acc);
  #pragma unroll
  for (int mi = 0; mi < 4; mi++) {
    #pragma unroll
    for (int r = 0; r < 4; r++) {
      int ml = mb + mi * 16 + quad * 4 + r;
      if (m0 + ml < cnt) {
        int tok = toks[ml] >> 1;
        float* orow = out + (size_t)tok * C + c0 + nb;
        #pragma unroll
        for (int ni = 0; ni < 4; ni++) atomicAdd(&orow[ni * 16 + col], acc[mi][ni][r]);
      }
    }
  }
}

// --------------------------------------------------- shared expert: k-proj
// kk = bf16( relu(rs2*(xt.k_w^T) + k_b)^2 )
__global__ void kproj_kernel(const bf16* __restrict__ xtb, const bf16* __restrict__ kwb,
                             const float* __restrict__ rs2, const float* __restrict__ k_b,
                             bf16* __restrict__ kkb) {
  const int n0 = blockIdx.x * BM;
  const int h0 = blockIdx.y * BN;
  GEMM_PROLOGUE
  const char* gA0 = (const char*)xtb + ((size_t)(n0 + sr0) * C) * 2 + scb;
  const char* gA1 = (const char*)xtb + ((size_t)(n0 + sr1) * C) * 2 + scb;
  const char* gB0 = (const char*)kwb + ((size_t)(h0 + sr0) * C) * 2 + scb;
  const char* gB1 = (const char*)kwb + ((size_t)(h0 + sr1) * C) * 2 + scb;
  mfma_loop(gA0, gA1, gB0, gB1, As, Bs, wave, lane, C / BK, mb, nb, acc);
  #pragma unroll
  for (int mi = 0; mi < 4; mi++) {
    #pragma unroll
    for (int r = 0; r < 4; r++) {
      int n = n0 + mb + mi * 16 + quad * 4 + r;
      float rs = rs2[n];
      #pragma unroll
      for (int ni = 0; ni < 4; ni++) {
        int h = h0 + nb + ni * 16 + col;
        float v = fmaf(acc[mi][ni][r], rs, k_b[h]);
        v = fmaxf(v, 0.f);
        kkb[(size_t)n * H + h] = (bf16)(v * v);
      }
    }
  }
}

// --------------------------------------------------- shared expert: v-proj
// out += sg * (kk.v_w^T + v_b)   (out already holds routed sum)
__global__ void vproj_kernel(const bf16* __restrict__ kkb, const bf16* __restrict__ vwb,
                             const float* __restrict__ v_b, const float* __restrict__ sg,
                             float* __restrict__ out) {
  const int n0 = blockIdx.x * BM;
  const int c0 = blockIdx.y * BN;
  GEMM_PROLOGUE
  const char* gA0 = (const char*)kkb + ((size_t)(n0 + sr0) * H) * 2 + scb;
  const char* gA1 = (const char*)kkb + ((size_t)(n0 + sr1) * H) * 2 + scb;
  const char* gB0 = (const char*)vwb + ((size_t)(c0 + sr0) * H) * 2 + scb;
  const char* gB1 = (const char*)vwb + ((size_t)(c0 + sr1) * H) * 2 + scb;
  mfma_loop(gA0, gA1, gB0, gB1, As, Bs, wave, lane, H / BK, mb, nb, acc);
  #pragma unroll
  for (int mi = 0; mi < 4; mi++) {
    #pragma unroll
    for (int r = 0; r < 4; r++) {
      int n = n0 + mb + mi * 16 + quad * 4 + r;
      float sgv = sg[n];
      #pragma unroll
      for (int ni = 0; ni < 4; ni++) {
        int c = c0 + nb + ni * 16 + col;
        size_t o = (size_t)n * C + c;
        out[o] = out[o] + sgv * (acc[mi][ni][r] + v_b[c]);
      }
    }
  }
}

// -------------------------------------------------------------------- aux
// onehot column-mean is exactly 0.5*counts[e]/N
__global__ void aux_kernel(const float* __restrict__ scoresums,
                           const int* __restrict__ counts,
                           float* __restrict__ out_aux) {
  if (threadIdx.x == 0) {
    float a = 0.f;
    for (int e = 0; e < 8; e++)
      a += (0.5f * (float)counts[e] * (1.f / N)) * (scoresums[e] * (1.f / N));
    out_aux[0] = 8.f * a * 0.01f;
  }
}

extern "C" void kernel_launch(void* const* d_in, const int* in_sizes, int n_in,
                              void* d_out, int out_size, void* d_ws, size_t ws_size,
                              hipStream_t stream) {
  (void)in_sizes; (void)n_in; (void)ws_size;
  const float* x   = (const float*)d_in[0];
  const float* gw  = (const float*)d_in[1];
  const float* w1  = (const float*)d_in[2];
  const float* w2  = (const float*)d_in[3];
  const float* sgw = (const float*)d_in[4];
  const float* k_w = (const float*)d_in[5];
  const float* k_b = (const float*)d_in[6];
  const float* v_w = (const float*)d_in[7];
  const float* v_b = (const float*)d_in[8];
  float* out = (float*)d_out;

  // workspace layout (~97 MiB)
  char* p = (char*)d_ws;
  auto alloc = [&](size_t bytes) { char* r = p; p += (bytes + 255) & ~255ull; return r; };
  bf16* xtb  = (bf16*)alloc((size_t)N * C * 2);
  bf16* w1b  = (bf16*)alloc((size_t)E * H * C * 2);
  bf16* w2b  = (bf16*)alloc((size_t)E * C * H * 2);
  bf16* kwb  = (bf16*)alloc((size_t)H * C * 2);
  bf16* vwb  = (bf16*)alloc((size_t)C * H * 2);
  bf16* hb   = (bf16*)alloc((size_t)2 * N * H * 2);  // [2N][H], packed-slot rows
  bf16* kkb  = hb;  // alias: down reads hb strictly before kproj writes kkb
  float* rs1 = (float*)alloc((size_t)N * 4);
  float* rs2 = (float*)alloc((size_t)N * 4);
  float* g   = (float*)alloc((size_t)N * E * 4);
  float* sg  = (float*)alloc((size_t)N * 4);
  float* scoresums = (float*)alloc(64);
  int* counts = (int*)alloc(64);
  int* lists  = (int*)alloc((size_t)E * N * 4);

  hipMemsetAsync(d_out, 0, (size_t)out_size * sizeof(float), stream);
  init_kernel<<<1, 32, 0, stream>>>(counts, scoresums);
  cvt_kernel<<<(E * H * C) / 1024, 256, 0, stream>>>(w1, w1b);
  cvt_kernel<<<(E * C * H) / 1024, 256, 0, stream>>>(w2, w2b);
  cvt_kernel<<<(H * C) / 1024, 256, 0, stream>>>(k_w, kwb);
  cvt_kernel<<<(C * H) / 1024, 256, 0, stream>>>(v_w, vwb);
  rmsnorm_kernel<<<N, 256, 0, stream>>>(x, xtb, rs1, rs2);
  gate_kernel<<<N / GT, 256, 0, stream>>>(x, rs1, gw, sgw, g, sg, counts, lists, scoresums);
  up_kernel<<<dim3(N / BM, E, H / BN), 256, 0, stream>>>(xtb, w1b, g, lists, counts, hb);
  down_kernel<<<dim3(N / BM, E, C / BN), 256, 0, stream>>>(hb, w2b, lists, counts, out);
  kproj_kernel<<<dim3(N / BM, H / BN), 256, 0, stream>>>(xtb, kwb, rs2, k_b, kkb);
  vproj_kernel<<<dim3(N / BM, C / BN), 256, 0, stream>>>(kkb, vwb, v_b, sg, out);
  aux_kernel<<<1, 64, 0, stream>>>(scoresums, counts, out + (size_t)N * C);
}